// Round 1
// 1352.060 us; speedup vs baseline: 1.1176x; 1.1176x over previous
//
#include <hip/hip_runtime.h>

// ToyMoE: E=8, T=1024, H=2048, I=4096.
// R3: both GEMMs rewritten as 8-wave 256-row-tile 4-phase-per-K-tile kernels
// (T3+T4 counted-vmcnt pipeline + T5 setprio), 128KB double-buffered LDS.
// Prefetch lands in dead half-tile regions: B(t+1)->other buf @ph1/2,
// A(t+2)->current buf @ph3/4 (A halves dead after ph2). Boundary wait is
// vmcnt(4) (2 half-tiles in flight), vmcnt(0) only at the last tiles.
// SwiGLU stays fused (output tile 256x128 hidden; Bg/Bu staged separately).
// cvt/transpose kernels unchanged from R2 (conflict-free swizzles verified).

#define E_ 8
#define T_ 1024
#define H_ 2048
#define I_ 4096

typedef unsigned short ushort_t;
typedef unsigned int uint_t;
typedef float f32x4 __attribute__((ext_vector_type(4)));
typedef __bf16 bf16x8 __attribute__((ext_vector_type(8)));
typedef unsigned short ushort8 __attribute__((ext_vector_type(8)));

__device__ inline ushort_t f2bf(float f) {
  uint_t u = __float_as_uint(f);
  u += 0x7fffu + ((u >> 16) & 1u);   // RTNE
  return (ushort_t)(u >> 16);
}

// async global->LDS, 16B per lane; LDS dest is wave-uniform base + lane*16
__device__ inline void async_copy16(void* lds, const void* gptr) {
  __builtin_amdgcn_global_load_lds(
      (__attribute__((address_space(1))) void*)(void*)gptr,
      (__attribute__((address_space(3))) void*)lds,
      16, 0, 0);
}

// Stage one 128-row x 64-col bf16 half-tile: 1024 chunks of 16B, 512 threads,
// 2 global_load_lds per thread. LDS linear; global source pre-swizzled so
// LDS 16B-chunk slot s holds global k-chunk (s&7)^((s>>3)&7) of row s>>3.
__device__ __forceinline__ void stage_half(ushort_t* lds, const ushort_t* g,
                                           int ld, int tid) {
#pragma unroll
  for (int r = 0; r < 2; ++r) {
    int chunk = r * 512 + tid;
    int row = chunk >> 3;
    int kc = ((chunk & 7) ^ (row & 7)) * 8;
    async_copy16(lds + chunk * 8, g + (size_t)row * ld + kc);
  }
}

// ---------------- fp32 -> bf16 straight convert (x) ----------------
__global__ __launch_bounds__(256) void cvt_kernel(const float* __restrict__ in,
                                                  ushort_t* __restrict__ out) {
  size_t base = (size_t)(blockIdx.x * 256 + threadIdx.x) * 8;
  f32x4 a = *(const f32x4*)(in + base);
  f32x4 b = *(const f32x4*)(in + base + 4);
  ushort8 o;
  o[0] = f2bf(a[0]); o[1] = f2bf(a[1]); o[2] = f2bf(a[2]); o[3] = f2bf(a[3]);
  o[4] = f2bf(b[0]); o[5] = f2bf(b[1]); o[6] = f2bf(b[2]); o[7] = f2bf(b[3]);
  *(ushort8*)(out + base) = o;
}

// -------- fp32 [E][R][C] -> bf16 [E][C][R] transpose+convert, 64x64 tile ----
__global__ __launch_bounds__(256) void transpose_kernel(
    const float* __restrict__ in, ushort_t* __restrict__ out, int R, int C) {
  __shared__ float tile[64 * 64];
  const int e = blockIdx.z;
  const float* inb = in + (size_t)e * R * C;
  ushort_t* outb = out + (size_t)e * R * C;
  const int c0 = blockIdx.x * 64, r0 = blockIdx.y * 64;
  const int t = threadIdx.x;
  const int lrow = t >> 4, lc4 = t & 15;
#pragma unroll
  for (int rr = 0; rr < 64; rr += 16) {
    int r = lrow + rr;
    f32x4 v = *(const f32x4*)&inb[(size_t)(r0 + r) * C + c0 + lc4 * 4];
    *(f32x4*)&tile[r * 64 + 4 * (lc4 ^ (r >> 3))] = v;
  }
  __syncthreads();
  const int oc = t >> 3, orr = (t & 7) * 8;
#pragma unroll
  for (int cc = 0; cc < 64; cc += 32) {
    int c = oc + cc;
    ushort8 o;
#pragma unroll
    for (int k = 0; k < 8; ++k) {
      int r = orr + k;
      o[k] = f2bf(tile[r * 64 + 4 * ((c >> 2) ^ (r >> 3)) + (c & 3)]);
    }
    *(ushort8*)&outb[(size_t)(c0 + c) * R + r0 + orr] = o;
  }
}

#define LGKM0() asm volatile("s_waitcnt lgkmcnt(0)" ::: "memory")

// ---------------- GEMM1 + bias + SwiGLU fused, 8-phase ----------------
// A=[E][T][H] bf16, B=wgu_t [E][2I][H] bf16 (N-major). Out hidden [E][T][I].
// Block: 256(M) x 128(N, hidden). 8 waves 2Mx4N; wave tile 128x32 (g AND u).
__global__ __launch_bounds__(512, 2) void gemm1_swiglu_kernel(
    const ushort_t* __restrict__ A, const ushort_t* __restrict__ B,
    const float* __restrict__ bias, ushort_t* __restrict__ Hd) {
  __shared__ ushort_t lds[2 * 32768];  // 128 KiB
  ushort_t* bA0 = lds;                  // 256x64 A
  ushort_t* bG0 = lds + 16384;          // 128x64 gate
  ushort_t* bU0 = lds + 24576;          // 128x64 up
  ushort_t* bA1 = lds + 32768;
  ushort_t* bG1 = lds + 49152;
  ushort_t* bU1 = lds + 57344;

  const int e = blockIdx.z;
  const int m0 = blockIdx.y * 256;
  const int n0 = blockIdx.x * 128;
  const ushort_t* Ab = A + (size_t)e * T_ * H_ + (size_t)m0 * H_;
  const ushort_t* Gb = B + (size_t)e * 2 * I_ * H_ + (size_t)n0 * H_;
  const ushort_t* Ub = B + (size_t)e * 2 * I_ * H_ + (size_t)(I_ + n0) * H_;
  const int tid = threadIdx.x;
  const int wv = tid >> 6, lane = tid & 63;
  const int wm = (wv >> 2) * 128;   // 0 / 128
  const int wn = (wv & 3) * 32;     // 0,32,64,96 (hidden cols)
  const int quad = lane >> 4, lr = lane & 15;

  f32x4 ag[8][2] = {};
  f32x4 au[8][2] = {};
  bf16x8 alo[4][2], ahi[4][2], bb[2][2];

  const int NT = H_ / 64;  // 32

  // prologue: tile0 fully + A halves of tile1 (12 loads; wait all but last 4)
  stage_half(bA0, Ab, H_, tid);
  stage_half(bA0 + 8192, Ab + 128 * H_, H_, tid);
  stage_half(bG0, Gb, H_, tid);
  stage_half(bU0, Ub, H_, tid);
  stage_half(bA1, Ab + 64, H_, tid);
  stage_half(bA1 + 8192, Ab + 128 * H_ + 64, H_, tid);
  asm volatile("s_waitcnt vmcnt(4)" ::: "memory");
  __builtin_amdgcn_s_barrier();
  __builtin_amdgcn_sched_barrier(0);

  auto tile = [&](int t, ushort_t* cA, ushort_t* cG, ushort_t* cU,
                  ushort_t* oG, ushort_t* oU) {
    // -------- phase 1: gate x lower-A; stage Bg(t+1) --------
#pragma unroll
    for (int mi = 0; mi < 4; ++mi)
#pragma unroll
      for (int ks = 0; ks < 2; ++ks)
        alo[mi][ks] = *(const bf16x8*)&cA[(wm + mi * 16 + lr) * 64 +
                                          (((ks * 4 + quad) ^ (lr & 7)) * 8)];
#pragma unroll
    for (int ni = 0; ni < 2; ++ni)
#pragma unroll
      for (int ks = 0; ks < 2; ++ks)
        bb[ni][ks] = *(const bf16x8*)&cG[(wn + ni * 16 + lr) * 64 +
                                         (((ks * 4 + quad) ^ (lr & 7)) * 8)];
    if (t + 1 < NT) stage_half(oG, Gb + (size_t)(t + 1) * 64, H_, tid);
    __builtin_amdgcn_s_barrier();
    LGKM0();
    __builtin_amdgcn_s_setprio(1);
#pragma unroll
    for (int ks = 0; ks < 2; ++ks)
#pragma unroll
      for (int mi = 0; mi < 4; ++mi)
#pragma unroll
        for (int ni = 0; ni < 2; ++ni)
          ag[mi][ni] = __builtin_amdgcn_mfma_f32_16x16x32_bf16(
              alo[mi][ks], bb[ni][ks], ag[mi][ni], 0, 0, 0);
    __builtin_amdgcn_s_setprio(0);
    __builtin_amdgcn_s_barrier();
    // -------- phase 2: gate x upper-A; stage Bu(t+1) --------
#pragma unroll
    for (int mi = 0; mi < 4; ++mi)
#pragma unroll
      for (int ks = 0; ks < 2; ++ks)
        ahi[mi][ks] = *(const bf16x8*)&cA[(wm + 64 + mi * 16 + lr) * 64 +
                                          (((ks * 4 + quad) ^ (lr & 7)) * 8)];
    if (t + 1 < NT) stage_half(oU, Ub + (size_t)(t + 1) * 64, H_, tid);
    __builtin_amdgcn_s_barrier();
    LGKM0();
    __builtin_amdgcn_s_setprio(1);
#pragma unroll
    for (int ks = 0; ks < 2; ++ks)
#pragma unroll
      for (int mi = 0; mi < 4; ++mi)
#pragma unroll
        for (int ni = 0; ni < 2; ++ni)
          ag[4 + mi][ni] = __builtin_amdgcn_mfma_f32_16x16x32_bf16(
              ahi[mi][ks], bb[ni][ks], ag[4 + mi][ni], 0, 0, 0);
    __builtin_amdgcn_s_setprio(0);
    __builtin_amdgcn_s_barrier();
    // -------- phase 3: up x lower-A; stage A-half0(t+2) into cA (dead) ----
#pragma unroll
    for (int ni = 0; ni < 2; ++ni)
#pragma unroll
      for (int ks = 0; ks < 2; ++ks)
        bb[ni][ks] = *(const bf16x8*)&cU[(wn + ni * 16 + lr) * 64 +
                                         (((ks * 4 + quad) ^ (lr & 7)) * 8)];
    if (t + 2 < NT) stage_half(cA, Ab + (size_t)(t + 2) * 64, H_, tid);
    __builtin_amdgcn_s_barrier();
    LGKM0();
    __builtin_amdgcn_s_setprio(1);
#pragma unroll
    for (int ks = 0; ks < 2; ++ks)
#pragma unroll
      for (int mi = 0; mi < 4; ++mi)
#pragma unroll
        for (int ni = 0; ni < 2; ++ni)
          au[mi][ni] = __builtin_amdgcn_mfma_f32_16x16x32_bf16(
              alo[mi][ks], bb[ni][ks], au[mi][ni], 0, 0, 0);
    __builtin_amdgcn_s_setprio(0);
    __builtin_amdgcn_s_barrier();
    // -------- phase 4: up x upper-A; stage A-half1(t+2); boundary wait ----
    if (t + 2 < NT)
      stage_half(cA + 8192, Ab + 128 * H_ + (size_t)(t + 2) * 64, H_, tid);
    __builtin_amdgcn_s_barrier();
    LGKM0();
    __builtin_amdgcn_s_setprio(1);
#pragma unroll
    for (int ks = 0; ks < 2; ++ks)
#pragma unroll
      for (int mi = 0; mi < 4; ++mi)
#pragma unroll
        for (int ni = 0; ni < 2; ++ni)
          au[4 + mi][ni] = __builtin_amdgcn_mfma_f32_16x16x32_bf16(
              ahi[mi][ks], bb[ni][ks], au[4 + mi][ni], 0, 0, 0);
    __builtin_amdgcn_s_setprio(0);
    if (t + 2 < NT)
      asm volatile("s_waitcnt vmcnt(4)" ::: "memory");
    else
      asm volatile("s_waitcnt vmcnt(0)" ::: "memory");
    __builtin_amdgcn_s_barrier();
    __builtin_amdgcn_sched_barrier(0);
  };

  for (int t = 0; t < NT; t += 2) {
    tile(t, bA0, bG0, bU0, bG1, bU1);
    tile(t + 1, bA1, bG1, bU1, bG0, bU0);
  }

  // epilogue: C/D layout col=lane&15, row=quad*4+reg (verified R1)
  ushort_t* Hb = Hd + (size_t)e * T_ * I_;
  const float* biasb = bias + (size_t)e * 2 * I_;
#pragma unroll
  for (int ni = 0; ni < 2; ++ni) {
    int col = n0 + wn + ni * 16 + lr;
    float bgv = biasb[col];
    float buv = biasb[I_ + col];
#pragma unroll
    for (int mi = 0; mi < 8; ++mi) {
      int rowb = m0 + wm + mi * 16 + quad * 4;
#pragma unroll
      for (int r = 0; r < 4; ++r) {
        float g = ag[mi][ni][r] + bgv;
        float u = au[mi][ni][r] + buv;
        float s = g / (1.0f + __expf(-g));
        Hb[(size_t)(rowb + r) * I_ + col] = f2bf(s * u);
      }
    }
  }
}

// ---------------- GEMM2: out = hidden @ Wd^T + bd, fp32 out, 8-phase -------
// A=hidden [E][T][I] bf16, B=wd_t [E][H][I] bf16, out [E][T][H] fp32.
// Block: 256(M) x 256(N). 8 waves 2Mx4N; wave tile 128x64.
__global__ __launch_bounds__(512, 2) void gemm2_kernel(
    const ushort_t* __restrict__ A, const ushort_t* __restrict__ B,
    const float* __restrict__ bias, float* __restrict__ C) {
  __shared__ ushort_t lds[2 * 32768];  // 128 KiB
  ushort_t* bA0 = lds;                  // 256x64 A
  ushort_t* bB0 = lds + 16384;          // 256x64 B
  ushort_t* bA1 = lds + 32768;
  ushort_t* bB1 = lds + 49152;

  const int e = blockIdx.z;
  const int m0 = blockIdx.y * 256;
  const int n0 = blockIdx.x * 256;
  const ushort_t* Ab = A + (size_t)e * T_ * I_ + (size_t)m0 * I_;
  const ushort_t* Bb = B + (size_t)e * H_ * I_ + (size_t)n0 * I_;
  const int tid = threadIdx.x;
  const int wv = tid >> 6, lane = tid & 63;
  const int wm = (wv >> 2) * 128;   // 0 / 128
  const int wn = (wv & 3) * 64;     // 0,64,128,192
  const int quad = lane >> 4, lr = lane & 15;

  f32x4 acc[8][4] = {};
  bf16x8 alo[4][2], ahi[4][2], bfr[2][2];

  const int NT = I_ / 64;  // 64

  // prologue
  stage_half(bA0, Ab, I_, tid);
  stage_half(bA0 + 8192, Ab + 128 * I_, I_, tid);
  stage_half(bB0, Bb, I_, tid);
  stage_half(bB0 + 8192, Bb + 128 * I_, I_, tid);
  stage_half(bA1, Ab + 64, I_, tid);
  stage_half(bA1 + 8192, Ab + 128 * I_ + 64, I_, tid);
  asm volatile("s_waitcnt vmcnt(4)" ::: "memory");
  __builtin_amdgcn_s_barrier();
  __builtin_amdgcn_sched_barrier(0);

  auto tile = [&](int t, ushort_t* cA, ushort_t* cB, ushort_t* oB) {
    // -------- phase 1: lower-A x B(ni 0,1); stage B-half0(t+1) --------
#pragma unroll
    for (int mi = 0; mi < 4; ++mi)
#pragma unroll
      for (int ks = 0; ks < 2; ++ks)
        alo[mi][ks] = *(const bf16x8*)&cA[(wm + mi * 16 + lr) * 64 +
                                          (((ks * 4 + quad) ^ (lr & 7)) * 8)];
#pragma unroll
    for (int ni = 0; ni < 2; ++ni)
#pragma unroll
      for (int ks = 0; ks < 2; ++ks)
        bfr[ni][ks] = *(const bf16x8*)&cB[(wn + ni * 16 + lr) * 64 +
                                          (((ks * 4 + quad) ^ (lr & 7)) * 8)];
    if (t + 1 < NT) stage_half(oB, Bb + (size_t)(t + 1) * 64, I_, tid);
    __builtin_amdgcn_s_barrier();
    LGKM0();
    __builtin_amdgcn_s_setprio(1);
#pragma unroll
    for (int ks = 0; ks < 2; ++ks)
#pragma unroll
      for (int mi = 0; mi < 4; ++mi)
#pragma unroll
        for (int ni = 0; ni < 2; ++ni)
          acc[mi][ni] = __builtin_amdgcn_mfma_f32_16x16x32_bf16(
              alo[mi][ks], bfr[ni][ks], acc[mi][ni], 0, 0, 0);
    __builtin_amdgcn_s_setprio(0);
    __builtin_amdgcn_s_barrier();
    // -------- phase 2: upper-A x B(ni 0,1); stage B-half1(t+1) --------
#pragma unroll
    for (int mi = 0; mi < 4; ++mi)
#pragma unroll
      for (int ks = 0; ks < 2; ++ks)
        ahi[mi][ks] = *(const bf16x8*)&cA[(wm + 64 + mi * 16 + lr) * 64 +
                                          (((ks * 4 + quad) ^ (lr & 7)) * 8)];
    if (t + 1 < NT)
      stage_half(oB + 8192, Bb + 128 * I_ + (size_t)(t + 1) * 64, I_, tid);
    __builtin_amdgcn_s_barrier();
    LGKM0();
    __builtin_amdgcn_s_setprio(1);
#pragma unroll
    for (int ks = 0; ks < 2; ++ks)
#pragma unroll
      for (int mi = 0; mi < 4; ++mi)
#pragma unroll
        for (int ni = 0; ni < 2; ++ni)
          acc[4 + mi][ni] = __builtin_amdgcn_mfma_f32_16x16x32_bf16(
              ahi[mi][ks], bfr[ni][ks], acc[4 + mi][ni], 0, 0, 0);
    __builtin_amdgcn_s_setprio(0);
    __builtin_amdgcn_s_barrier();
    // -------- phase 3: lower-A x B(ni 2,3); stage A-half0(t+2) --------
#pragma unroll
    for (int ni = 0; ni < 2; ++ni)
#pragma unroll
      for (int ks = 0; ks < 2; ++ks)
        bfr[ni][ks] = *(const bf16x8*)&cB[(wn + 32 + ni * 16 + lr) * 64 +
                                          (((ks * 4 + quad) ^ (lr & 7)) * 8)];
    if (t + 2 < NT) stage_half(cA, Ab + (size_t)(t + 2) * 64, I_, tid);
    __builtin_amdgcn_s_barrier();
    LGKM0();
    __builtin_amdgcn_s_setprio(1);
#pragma unroll
    for (int ks = 0; ks < 2; ++ks)
#pragma unroll
      for (int mi = 0; mi < 4; ++mi)
#pragma unroll
        for (int ni = 0; ni < 2; ++ni)
          acc[mi][2 + ni] = __builtin_amdgcn_mfma_f32_16x16x32_bf16(
              alo[mi][ks], bfr[ni][ks], acc[mi][2 + ni], 0, 0, 0);
    __builtin_amdgcn_s_setprio(0);
    __builtin_amdgcn_s_barrier();
    // -------- phase 4: upper-A x B(ni 2,3); stage A-half1(t+2); boundary --
    if (t + 2 < NT)
      stage_half(cA + 8192, Ab + 128 * I_ + (size_t)(t + 2) * 64, I_, tid);
    __builtin_amdgcn_s_barrier();
    LGKM0();
    __builtin_amdgcn_s_setprio(1);
#pragma unroll
    for (int ks = 0; ks < 2; ++ks)
#pragma unroll
      for (int mi = 0; mi < 4; ++mi)
#pragma unroll
        for (int ni = 0; ni < 2; ++ni)
          acc[4 + mi][2 + ni] = __builtin_amdgcn_mfma_f32_16x16x32_bf16(
              ahi[mi][ks], bfr[ni][ks], acc[4 + mi][2 + ni], 0, 0, 0);
    __builtin_amdgcn_s_setprio(0);
    if (t + 2 < NT)
      asm volatile("s_waitcnt vmcnt(4)" ::: "memory");
    else
      asm volatile("s_waitcnt vmcnt(0)" ::: "memory");
    __builtin_amdgcn_s_barrier();
    __builtin_amdgcn_sched_barrier(0);
  };

  for (int t = 0; t < NT; t += 2) {
    tile(t, bA0, bB0, bB1);
    tile(t + 1, bA1, bB1, bB0);
  }

  float* Cb = C + (size_t)e * T_ * H_;
  const float* biasb = bias + (size_t)e * H_;
#pragma unroll
  for (int ni = 0; ni < 4; ++ni) {
    int col = n0 + wn + ni * 16 + lr;
    float bv = biasb[col];
#pragma unroll
    for (int mi = 0; mi < 8; ++mi) {
      int rowb = m0 + wm + mi * 16 + quad * 4;
#pragma unroll
      for (int r = 0; r < 4; ++r)
        Cb[(size_t)(rowb + r) * H_ + col] = acc[mi][ni][r] + bv;
    }
  }
}

extern "C" void kernel_launch(void* const* d_in, const int* in_sizes, int n_in,
                              void* d_out, int out_size, void* d_ws, size_t ws_size,
                              hipStream_t stream) {
  const float* x   = (const float*)d_in[0];  // [E][T][H]
  const float* wgu = (const float*)d_in[1];  // [E][H][2I]
  const float* bgu = (const float*)d_in[2];  // [E][2I]
  const float* wd  = (const float*)d_in[3];  // [E][I][H]
  const float* bd  = (const float*)d_in[4];  // [E][H]
  float* out = (float*)d_out;                // [E][T][H]

  char* ws = (char*)d_ws;
  // workspace: xb 32MB | wgu_t 256MB | wd_t 128MB | hidden 64MB = 480MB
  ushort_t* xb     = (ushort_t*)(ws);
  ushort_t* wgu_t  = (ushort_t*)(ws + 33554432);
  ushort_t* wd_t   = (ushort_t*)(ws + 33554432 + 268435456);
  ushort_t* hidden = (ushort_t*)(ws + 33554432 + 268435456 + 134217728);

  cvt_kernel<<<8192, 256, 0, stream>>>(x, xb);
  transpose_kernel<<<dim3(2 * I_ / 64, H_ / 64, E_), 256, 0, stream>>>(
      wgu, wgu_t, H_, 2 * I_);
  transpose_kernel<<<dim3(H_ / 64, I_ / 64, E_), 256, 0, stream>>>(
      wd, wd_t, I_, H_);
  gemm1_swiglu_kernel<<<dim3(I_ / 128, T_ / 256, E_), 512, 0, stream>>>(
      xb, wgu_t, bgu, hidden);
  gemm2_kernel<<<dim3(H_ / 256, T_ / 256, E_), 512, 0, stream>>>(
      hidden, wd_t, bd, out);
}